// Round 1
// baseline (534.055 us; speedup 1.0000x reference)
//
#include <hip/hip_runtime.h>
#include <hip/hip_bf16.h>
#include <stdint.h>
#include <stddef.h>

// ---------- types ----------
typedef __attribute__((ext_vector_type(8))) __bf16 bf16x8;   // MFMA A/B frag (4 VGPRs)
typedef __attribute__((ext_vector_type(4))) float  f32x4;    // MFMA C/D frag
typedef __attribute__((ext_vector_type(8))) unsigned short ushort8;

typedef const void __attribute__((address_space(1)))* as1_cvp;
typedef void       __attribute__((address_space(3)))* as3_vp;

__device__ __forceinline__ void gload_lds16(const void* g, void* l) {
    // width=16: emits global_load_lds_dwordx4. LDS dest = wave-uniform base + lane*16.
    __builtin_amdgcn_global_load_lds((as1_cvp)g, (as3_vp)l, 16, 0, 0);
}

__device__ __forceinline__ unsigned short f2bf(float f) {
    union { float f; unsigned u; } v; v.f = f;
    unsigned r = v.u + 0x7fffu + ((v.u >> 16) & 1u);   // RNE
    return (unsigned short)(r >> 16);
}

// ---------- kernel 1: x fp32 -> bf16 ----------
__global__ __launch_bounds__(256) void cast_x_kernel(
    const float* __restrict__ src, unsigned short* __restrict__ dst, int n8)
{
    int i = blockIdx.x * 256 + threadIdx.x;
    if (i >= n8) return;
    const float4* s = (const float4*)src + (size_t)i * 2;
    float4 a = s[0], c = s[1];
    ushort8 o;
    o[0] = f2bf(a.x); o[1] = f2bf(a.y); o[2] = f2bf(a.z); o[3] = f2bf(a.w);
    o[4] = f2bf(c.x); o[5] = f2bf(c.y); o[6] = f2bf(c.z); o[7] = f2bf(c.w);
    ((ushort8*)dst)[i] = o;
}

// ---------- kernel 2: Wb = bf16(W + [0; B1@A1; B2@A2]) ----------
// one block per output row o; 256 threads x 8 cols
__global__ __launch_bounds__(256) void prep_w_kernel(
    const float* __restrict__ W,
    const float* __restrict__ A1, const float* __restrict__ B1,
    const float* __restrict__ A2, const float* __restrict__ B2,
    unsigned short* __restrict__ Wb, int d)
{
    int o  = blockIdx.x;
    int k0 = threadIdx.x * 8;
    const float4* wrow = (const float4*)(W + (size_t)o * d + k0);
    float4 w0 = wrow[0], w1 = wrow[1];
    float acc[8] = {w0.x, w0.y, w0.z, w0.w, w1.x, w1.y, w1.z, w1.w};
    if (o >= d) {                               // block-uniform branch
        const float* A  = (o < 2 * d) ? A1 : A2;    // [8, d]
        const float* Bm = (o < 2 * d) ? B1 : B2;    // [d, 8]
        int r0 = o - ((o < 2 * d) ? d : 2 * d);
#pragma unroll
        for (int r = 0; r < 8; ++r) {
            float bb = Bm[(size_t)r0 * 8 + r];
            const float4* arow = (const float4*)(A + (size_t)r * d + k0);
            float4 a0 = arow[0], a1 = arow[1];
            acc[0] += bb * a0.x; acc[1] += bb * a0.y;
            acc[2] += bb * a0.z; acc[3] += bb * a0.w;
            acc[4] += bb * a1.x; acc[5] += bb * a1.y;
            acc[6] += bb * a1.z; acc[7] += bb * a1.w;
        }
    }
    ushort8 ov;
#pragma unroll
    for (int c = 0; c < 8; ++c) ov[c] = f2bf(acc[c]);
    ((ushort8*)(Wb + (size_t)o * d))[threadIdx.x] = ov;
}

// ---------- kernel 3: C[M,N] = Xb[M,K] * Wb[N,K]^T + bias ----------
// 128x128 tile, BK=32, 256 thr = 4 waves, each wave 64x64 via 4x4 of 16x16x32 MFMA.
// LDS tiles stored as 16B chunks with XOR swizzle c' = c ^ ((m>>1)&3) to spread
// ds_read_b128 start-banks (2-way max aliasing = free) while keeping the
// lane-linear layout global_load_lds requires.
constexpr int BM = 128, BN = 128, BK = 32;

__global__ __launch_bounds__(256) void gemm_bt_kernel(
    const unsigned short* __restrict__ Xb,
    const unsigned short* __restrict__ Wb,
    const float* __restrict__ bias,
    float* __restrict__ out,
    int M, int N, int K)
{
    __shared__ __align__(16) unsigned short As[BM * BK];  // 8 KiB
    __shared__ __align__(16) unsigned short Bs[BN * BK];  // 8 KiB

    const int tid  = threadIdx.x;
    const int wave = tid >> 6;
    const int lane = tid & 63;
    const int quad = lane >> 4;
    const int lr   = lane & 15;

    const int bm = blockIdx.y * BM;
    const int bn = blockIdx.x * BN;

    // ---- staging assignment: 512 16B-chunks per tile; chunk L = t*256 + wave*64 + lane
    const unsigned short* gA[2];
    const unsigned short* gB[2];
    unsigned short* ldsA[2];
    unsigned short* ldsB[2];
#pragma unroll
    for (int t = 0; t < 2; ++t) {
        int L = t * 256 + wave * 64 + lane;
        int m = L >> 2;                       // row within tile
        int p = L & 3;                        // LDS chunk slot within row
        int c = p ^ ((m >> 1) & 3);           // global k-chunk (XOR involution)
        gA[t] = Xb + (size_t)(bm + m) * K + c * 8;
        gB[t] = Wb + (size_t)(bn + m) * K + c * 8;
        ldsA[t] = &As[(t * 256 + wave * 64) * 8];   // wave-uniform base
        ldsB[t] = &Bs[(t * 256 + wave * 64) * 8];
    }

    const int wm = (wave & 1) * 64;
    const int wn = (wave >> 1) * 64;

    // ---- fragment LDS byte offsets (constant across K iterations)
    int offA[4], offB[4];
#pragma unroll
    for (int i = 0; i < 4; ++i) {
        int m = wm + i * 16 + lr;
        offA[i] = (m * 4 + (quad ^ ((m >> 1) & 3))) * 8;  // in shorts
        int n = wn + i * 16 + lr;
        offB[i] = (n * 4 + (quad ^ ((n >> 1) & 3))) * 8;
    }

    f32x4 acc[4][4];
#pragma unroll
    for (int i = 0; i < 4; ++i)
#pragma unroll
        for (int j = 0; j < 4; ++j)
            acc[i][j] = (f32x4){0.f, 0.f, 0.f, 0.f};

    for (int kt = 0; kt < K; kt += BK) {
        gload_lds16(gA[0], ldsA[0]);
        gload_lds16(gA[1], ldsA[1]);
        gload_lds16(gB[0], ldsB[0]);
        gload_lds16(gB[1], ldsB[1]);
        gA[0] += BK; gA[1] += BK; gB[0] += BK; gB[1] += BK;
        __syncthreads();   // drains vmcnt -> LDS tiles complete

        bf16x8 af[4], bf[4];
#pragma unroll
        for (int i = 0; i < 4; ++i) af[i] = *(const bf16x8*)&As[offA[i]];
#pragma unroll
        for (int j = 0; j < 4; ++j) bf[j] = *(const bf16x8*)&Bs[offB[j]];
#pragma unroll
        for (int i = 0; i < 4; ++i)
#pragma unroll
            for (int j = 0; j < 4; ++j)
                acc[i][j] = __builtin_amdgcn_mfma_f32_16x16x32_bf16(
                    af[i], bf[j], acc[i][j], 0, 0, 0);
        __syncthreads();   // reads done before next stage overwrites
    }

    // ---- epilogue: C/D layout col=lane&15, row=quad*4+reg (m89-verified)
#pragma unroll
    for (int j = 0; j < 4; ++j) {
        int col = bn + wn + j * 16 + lr;
        float bv = bias[col];
#pragma unroll
        for (int i = 0; i < 4; ++i) {
            int row = bm + wm + i * 16 + quad * 4;
            float* op = out + (size_t)row * N + col;
#pragma unroll
            for (int r = 0; r < 4; ++r)
                op[(size_t)r * N] = acc[i][j][r] + bv;
        }
    }
}

// ---------- launcher ----------
extern "C" void kernel_launch(void* const* d_in, const int* in_sizes, int n_in,
                              void* d_out, int out_size, void* d_ws, size_t ws_size,
                              hipStream_t stream) {
    const float* x  = (const float*)d_in[0];   // [4,2048,2048]
    const float* W  = (const float*)d_in[1];   // [6144,2048]
    const float* b  = (const float*)d_in[2];   // [6144]
    const float* A1 = (const float*)d_in[3];   // [8,2048]
    const float* B1 = (const float*)d_in[4];   // [2048,8]
    const float* A2 = (const float*)d_in[5];   // [8,2048]
    const float* B2 = (const float*)d_in[6];   // [2048,8]
    float* out = (float*)d_out;

    const int d = 2048;
    const int K = d;              // in_features
    const int N = 3 * d;          // 6144 fused rows
    const int M = in_sizes[0] / d; // 8192 = B*S

    unsigned short* Xbf = (unsigned short*)d_ws;              // M*K bf16 = 33.5 MB
    unsigned short* Wbf = Xbf + (size_t)M * K;                // N*K bf16 = 25.2 MB

    // 1) x -> bf16
    int n8 = (M * K) / 8;
    cast_x_kernel<<<(n8 + 255) / 256, 256, 0, stream>>>(x, Xbf, n8);

    // 2) fused weight (W + LoRA delta) -> bf16
    prep_w_kernel<<<N, 256, 0, stream>>>(W, A1, B1, A2, B2, Wbf, d);

    // 3) GEMM + bias
    dim3 grid(N / BN, M / BM);    // (48, 64)
    gemm_bt_kernel<<<grid, 256, 0, stream>>>(Xbf, Wbf, b, out, M, N, K);
}

// Round 2
// 505.233 us; speedup vs baseline: 1.0570x; 1.0570x over previous
//
#include <hip/hip_runtime.h>
#include <hip/hip_bf16.h>
#include <stdint.h>
#include <stddef.h>

// ---------- types ----------
typedef __attribute__((ext_vector_type(8)))  __bf16 bf16x8;   // MFMA A/B frag (4 VGPRs)
typedef __attribute__((ext_vector_type(16))) float  f32x16;   // 32x32 MFMA C/D frag
typedef __attribute__((ext_vector_type(8)))  unsigned short ushort8;

typedef const void __attribute__((address_space(1)))* as1_cvp;
typedef void       __attribute__((address_space(3)))* as3_vp;

__device__ __forceinline__ void gload_lds16(const void* g, void* l) {
    // width=16 -> global_load_lds_dwordx4. LDS dest = wave-uniform base + lane*16.
    __builtin_amdgcn_global_load_lds((as1_cvp)g, (as3_vp)l, 16, 0, 0);
}

__device__ __forceinline__ unsigned short f2bf(float f) {
    union { float f; unsigned u; } v; v.f = f;
    unsigned r = v.u + 0x7fffu + ((v.u >> 16) & 1u);   // RNE
    return (unsigned short)(r >> 16);
}

// ---------- kernel 1 (fused prep): blocks [0,nW) -> Wb row; blocks [nW,..) -> x cast ----------
__global__ __launch_bounds__(256) void prep_kernel(
    const float* __restrict__ x,
    const float* __restrict__ W,
    const float* __restrict__ A1, const float* __restrict__ B1,
    const float* __restrict__ A2, const float* __restrict__ B2,
    unsigned short* __restrict__ Xb, unsigned short* __restrict__ Wb,
    int d, int nW, int n8)
{
    int blk = blockIdx.x;
    if (blk < nW) {
        // ---- Wb[o] = bf16(W[o] + LoRA delta[o]) ----
        int o  = blk;
        int k0 = threadIdx.x * 8;
        const float4* wrow = (const float4*)(W + (size_t)o * d + k0);
        float4 w0 = wrow[0], w1 = wrow[1];
        float acc[8] = {w0.x, w0.y, w0.z, w0.w, w1.x, w1.y, w1.z, w1.w};
        if (o >= d) {                               // block-uniform branch
            const float* A  = (o < 2 * d) ? A1 : A2;    // [8, d]
            const float* Bm = (o < 2 * d) ? B1 : B2;    // [d, 8]
            int r0 = o - ((o < 2 * d) ? d : 2 * d);
#pragma unroll
            for (int r = 0; r < 8; ++r) {
                float bb = Bm[(size_t)r0 * 8 + r];
                const float4* arow = (const float4*)(A + (size_t)r * d + k0);
                float4 a0 = arow[0], a1 = arow[1];
                acc[0] += bb * a0.x; acc[1] += bb * a0.y;
                acc[2] += bb * a0.z; acc[3] += bb * a0.w;
                acc[4] += bb * a1.x; acc[5] += bb * a1.y;
                acc[6] += bb * a1.z; acc[7] += bb * a1.w;
            }
        }
        ushort8 ov;
#pragma unroll
        for (int c = 0; c < 8; ++c) ov[c] = f2bf(acc[c]);
        ((ushort8*)(Wb + (size_t)o * d))[threadIdx.x] = ov;
    } else {
        // ---- Xb = bf16(x), 8 elems/thread ----
        int i = (blk - nW) * 256 + threadIdx.x;
        if (i >= n8) return;
        const float4* s = (const float4*)x + (size_t)i * 2;
        float4 a = s[0], c = s[1];
        ushort8 o;
        o[0] = f2bf(a.x); o[1] = f2bf(a.y); o[2] = f2bf(a.z); o[3] = f2bf(a.w);
        o[4] = f2bf(c.x); o[5] = f2bf(c.y); o[6] = f2bf(c.z); o[7] = f2bf(c.w);
        ((ushort8*)Xb)[i] = o;
    }
}

// ---------- kernel 2: C[M,N] = Xb[M,K] * Wb[N,K]^T + bias ----------
// 128x128 tile, BK=64, 256 thr = 4 waves, each wave 64x64 via 2x2 of 32x32x16 MFMA.
// LDS rows stored as 8 x 16B chunks, chunk swizzle c' = c ^ (row&7):
// any lane-octet's ds_read_b128 start-banks hit >=4 distinct groups, <=2-way
// aliasing (free per m136), while keeping the lane-linear layout
// global_load_lds requires. Staging addresses: uniform (SGPR) base advanced
// by the K loop + per-thread constant offset.
constexpr int BM = 128, BN = 128, BK = 64;

__global__ __launch_bounds__(256) void gemm_bt_kernel(
    const unsigned short* __restrict__ Xb,
    const unsigned short* __restrict__ Wb,
    const float* __restrict__ bias,
    float* __restrict__ out,
    int M, int N, int K)
{
    __shared__ __align__(16) unsigned short As[BM * BK];  // 16 KiB
    __shared__ __align__(16) unsigned short Bs[BN * BK];  // 16 KiB

    const int tid  = threadIdx.x;
    const int wave = tid >> 6;
    const int lane = tid & 63;
    const int half = lane >> 5;      // k-half selector for 32x32 frags
    const int ln32 = lane & 31;

    const int bm = blockIdx.y * BM;
    const int bn = blockIdx.x * BN;

    // ---- staging: 1024 chunks/tile; thread covers L = t*256 + tid, t=0..3
    // row m = L>>3 = t*32 + (tid>>3); slot p = tid&7; global chunk c = p ^ (m&7)
    const int m0 = tid >> 3;
    const int c0 = (tid & 7) ^ (m0 & 7);          // (t*32 + m0)&7 == m0&7
    const size_t goff = (size_t)m0 * K + c0 * 8;  // per-thread constant (elements)

    const int wm = (wave & 1) * 64;
    const int wn = (wave >> 1) * 64;

    // ---- fragment LDS offsets (shorts): row*64 + ((s*2+half)^(row&7))*8
    // row&7 == ln32&7 for all frags (wm, i*32 are multiples of 8)
    const int r7 = ln32 & 7;
    int dofs[4];
#pragma unroll
    for (int s = 0; s < 4; ++s) dofs[s] = ((s * 2 + half) ^ r7) * 8;
    int baseA[2], baseB[2];
#pragma unroll
    for (int i = 0; i < 2; ++i) {
        baseA[i] = (wm + i * 32 + ln32) * 64;
        baseB[i] = (wn + i * 32 + ln32) * 64;
    }

    f32x16 acc[2][2];
#pragma unroll
    for (int i = 0; i < 2; ++i)
#pragma unroll
        for (int j = 0; j < 2; ++j)
#pragma unroll
            for (int r = 0; r < 16; ++r) acc[i][j][r] = 0.f;

    for (int kt = 0; kt < K; kt += BK) {
        const unsigned short* pa = Xb + (size_t)bm * K + kt + goff;
        const unsigned short* pb = Wb + (size_t)bn * K + kt + goff;
#pragma unroll
        for (int t = 0; t < 4; ++t) {
            gload_lds16(pa + (size_t)t * 32 * K, &As[(t * 256 + wave * 64) * 8]);
            gload_lds16(pb + (size_t)t * 32 * K, &Bs[(t * 256 + wave * 64) * 8]);
        }
        __syncthreads();   // drains vmcnt -> LDS tiles complete

#pragma unroll
        for (int s = 0; s < 4; ++s) {
            bf16x8 a0 = *(const bf16x8*)&As[baseA[0] + dofs[s]];
            bf16x8 a1 = *(const bf16x8*)&As[baseA[1] + dofs[s]];
            bf16x8 b0 = *(const bf16x8*)&Bs[baseB[0] + dofs[s]];
            bf16x8 b1 = *(const bf16x8*)&Bs[baseB[1] + dofs[s]];
            acc[0][0] = __builtin_amdgcn_mfma_f32_32x32x16_bf16(a0, b0, acc[0][0], 0, 0, 0);
            acc[0][1] = __builtin_amdgcn_mfma_f32_32x32x16_bf16(a0, b1, acc[0][1], 0, 0, 0);
            acc[1][0] = __builtin_amdgcn_mfma_f32_32x32x16_bf16(a1, b0, acc[1][0], 0, 0, 0);
            acc[1][1] = __builtin_amdgcn_mfma_f32_32x32x16_bf16(a1, b1, acc[1][1], 0, 0, 0);
        }
        __syncthreads();   // reads done before next stage overwrites
    }

    // ---- epilogue: C/D layout col=lane&31, row=(reg&3)+8*(reg>>2)+4*half (m74/m101)
#pragma unroll
    for (int j = 0; j < 2; ++j) {
        int col = bn + wn + j * 32 + ln32;
        float bv = bias[col];
#pragma unroll
        for (int i = 0; i < 2; ++i) {
            int rbase = bm + wm + i * 32 + 4 * half;
#pragma unroll
            for (int reg = 0; reg < 16; ++reg) {
                int row = rbase + (reg & 3) + 8 * (reg >> 2);
                out[(size_t)row * N + col] = acc[i][j][reg] + bv;
            }
        }
    }
}

// ---------- launcher ----------
extern "C" void kernel_launch(void* const* d_in, const int* in_sizes, int n_in,
                              void* d_out, int out_size, void* d_ws, size_t ws_size,
                              hipStream_t stream) {
    const float* x  = (const float*)d_in[0];   // [4,2048,2048]
    const float* W  = (const float*)d_in[1];   // [6144,2048]
    const float* b  = (const float*)d_in[2];   // [6144]
    const float* A1 = (const float*)d_in[3];   // [8,2048]
    const float* B1 = (const float*)d_in[4];   // [2048,8]
    const float* A2 = (const float*)d_in[5];   // [8,2048]
    const float* B2 = (const float*)d_in[6];   // [2048,8]
    float* out = (float*)d_out;

    const int d = 2048;
    const int K = d;               // in_features
    const int N = 3 * d;           // 6144 fused rows
    const int M = in_sizes[0] / d; // 8192 = B*S

    unsigned short* Xbf = (unsigned short*)d_ws;              // M*K bf16 = 33.5 MB
    unsigned short* Wbf = Xbf + (size_t)M * K;                // N*K bf16 = 25.2 MB

    // 1) fused: Wb = bf16(W + delta); Xb = bf16(x)
    int n8 = (M * K) / 8;
    int castBlocks = (n8 + 255) / 256;
    prep_kernel<<<N + castBlocks, 256, 0, stream>>>(x, W, A1, B1, A2, B2,
                                                    Xbf, Wbf, d, N, n8);

    // 2) GEMM + bias
    dim3 grid(N / BN, M / BM);    // (48, 64)
    gemm_bt_kernel<<<grid, 256, 0, stream>>>(Xbf, Wbf, b, out, M, N, K);
}